// Round 1
// 6410.348 us; speedup vs baseline: 2.1011x; 2.1011x over previous
//
#include <hip/hip_runtime.h>
#include <math.h>

// ---------------------------------------------------------------------------
// ChatModel forward on MI355X.
// Precision strategy: all big GEMMs use f16x2 "split" MFMA:
//   x = hi + lo/2048   (lo stored pre-scaled by 2048 -> stays fp16-normal)
//   B (weights ~0.02) additionally pre-scaled by 256.
//   D = acc_hh/256 + acc_cross/(256*2048); 3 mfma per fragment pair.
// This round: weights are pre-split + pre-transposed ONCE per use by
// wsplit_kernel into f16 hi/lo B^T buffers, so the GEMM inner loop stages
// both A and B with pure 16B vector copies (no f32 fetch, no per-tile
// conversion VALU, no scalar transposed LDS writes / bank conflicts).
// ---------------------------------------------------------------------------

typedef _Float16 f16;
typedef _Float16 f16x8 __attribute__((ext_vector_type(8)));
typedef _Float16 f16x4 __attribute__((ext_vector_type(4)));
typedef float f32x4 __attribute__((ext_vector_type(4)));

#define NT 2048      // B*S tokens
#define HH 1024      // hidden
#define NHEAD 16
#define HDIM 64
#define NL 4
#define FFD 2560
#define NE 4
#define NV 32000
#define LMCH 6400    // lm_head column chunk (5 chunks of 6400 = 32000)

__device__ __forceinline__ void split_f32(float x, f16& h, f16& l) {
  h = (f16)x;
  l = (f16)((x - (float)h) * 2048.0f);
}

// ---------------------------------------------------------------------------
// Weight pre-pass: B[K][N] f32 (row stride ldb) -> BT hi/lo [N][K] f16,
// scaled by 256 and split. Tiled 32x32 transpose through LDS.
// grid: (N/32, K/32), block 256.
// ---------------------------------------------------------------------------
__global__ __launch_bounds__(256) void wsplit_kernel(
    const float* __restrict__ B, int ldb,
    f16* __restrict__ th, f16* __restrict__ tl, int K)
{
  __shared__ float t[32][33];
  const int bn = blockIdx.x * 32, bk = blockIdx.y * 32;
  const int c = threadIdx.x & 31, r0 = (threadIdx.x >> 5) * 4;
#pragma unroll
  for (int i = 0; i < 4; i++)
    t[r0 + i][c] = B[(size_t)(bk + r0 + i) * ldb + bn + c];
  __syncthreads();
#pragma unroll
  for (int i = 0; i < 4; i++) {
    int n = r0 + i;
    float v = t[c][n] * 256.0f;
    f16 h = (f16)v;
    f16 l = (f16)((v - (float)h) * 2048.0f);
    size_t o = (size_t)(bn + n) * K + bk + c;
    th[o] = h; tl[o] = l;
  }
}

// ---------------------------------------------------------------------------
// Split-precision GEMM: C[M,N] = A[M,K] (split f16 hi/lo) * B^T[N,K] (split).
// blockIdx.z selects weight (Bh + z*bstride) and C/bias pointer.
// mode 0: C = v (+bias)   mode 1: C += v   mode 2: C += rowscale[row]*(v+bias)
// ---------------------------------------------------------------------------
#define BM 128
#define BN 128
#define BK 32
#define LDP 40   // padded LDS leading dim (f16 elems); 80B row stride, 16B-aligned

__global__ __launch_bounds__(256, 2) void gemm_split(
    const f16* __restrict__ Ahi, const f16* __restrict__ Alo,
    const f16* __restrict__ Bh, const f16* __restrict__ Bl,
    unsigned long long bstride,
    float* __restrict__ C0, float* __restrict__ C1, float* __restrict__ C2,
    const float* __restrict__ bias0, const float* __restrict__ bias1,
    const float* __restrict__ bias2,
    const float* __restrict__ rowscale, int rs_stride,
    int M, int N, int K, int ldc, int mode)
{
  const int z = blockIdx.z;
  const f16* Bhz = Bh + (size_t)z * bstride;
  const f16* Blz = Bl + (size_t)z * bstride;
  float* Cm = (z == 0) ? C0 : (z == 1 ? C1 : C2);
  const float* bz = (z == 0) ? bias0 : (z == 1 ? bias1 : bias2);

  __shared__ f16 AsH[BM * LDP], AsL[BM * LDP], BsH[BN * LDP], BsL[BN * LDP];

  const int tid = threadIdx.x;
  const int m0 = blockIdx.y * BM, n0 = blockIdx.x * BN;
  const int wave = tid >> 6, lane = tid & 63, quad = lane >> 4, l15 = lane & 15;
  const int wm = (wave >> 1) * 64, wn = (wave & 1) * 64;

  f32x4 acc0[4][4], acc1[4][4];
#pragma unroll
  for (int i = 0; i < 4; i++)
#pragma unroll
    for (int j = 0; j < 4; j++) {
      acc0[i][j] = (f32x4){0.f, 0.f, 0.f, 0.f};
      acc1[i][j] = (f32x4){0.f, 0.f, 0.f, 0.f};
    }

  for (int kt = 0; kt < K; kt += BK) {
    // stage A and B^T: 128x32 f16 per array, pure 16B vector copies
#pragma unroll
    for (int i = 0; i < 2; i++) {
      int idx = tid + i * 256;              // 0..511 chunks of 8 f16
      int row = idx >> 2, col = (idx & 3) * 8;
      size_t ga = (size_t)(m0 + row) * K + kt + col;
      *(uint4*)&AsH[row * LDP + col] = *(const uint4*)&Ahi[ga];
      *(uint4*)&AsL[row * LDP + col] = *(const uint4*)&Alo[ga];
      size_t gb = (size_t)(n0 + row) * K + kt + col;
      *(uint4*)&BsH[row * LDP + col] = *(const uint4*)&Bhz[gb];
      *(uint4*)&BsL[row * LDP + col] = *(const uint4*)&Blz[gb];
    }
    __syncthreads();

    f16x8 bh[4], bl[4];
#pragma unroll
    for (int in = 0; in < 4; in++) {
      int r = wn + in * 16 + l15;
      bh[in] = *(const f16x8*)&BsH[r * LDP + quad * 8];
      bl[in] = *(const f16x8*)&BsL[r * LDP + quad * 8];
    }
#pragma unroll
    for (int im = 0; im < 4; im++) {
      int r = wm + im * 16 + l15;
      f16x8 ah = *(const f16x8*)&AsH[r * LDP + quad * 8];
      f16x8 al = *(const f16x8*)&AsL[r * LDP + quad * 8];
#pragma unroll
      for (int in = 0; in < 4; in++) {
        acc0[im][in] = __builtin_amdgcn_mfma_f32_16x16x32_f16(ah, bh[in], acc0[im][in], 0, 0, 0);
        acc1[im][in] = __builtin_amdgcn_mfma_f32_16x16x32_f16(ah, bl[in], acc1[im][in], 0, 0, 0);
        acc1[im][in] = __builtin_amdgcn_mfma_f32_16x16x32_f16(al, bh[in], acc1[im][in], 0, 0, 0);
      }
    }
    __syncthreads();
  }

  const float inv0 = 1.0f / 256.0f, inv1 = 1.0f / (256.0f * 2048.0f);
#pragma unroll
  for (int im = 0; im < 4; im++)
#pragma unroll
    for (int in = 0; in < 4; in++)
#pragma unroll
      for (int r = 0; r < 4; r++) {
        int row = m0 + wm + im * 16 + quad * 4 + r;
        int col = n0 + wn + in * 16 + l15;
        float v = acc0[im][in][r] * inv0 + acc1[im][in][r] * inv1;
        size_t o = (size_t)row * ldc + col;
        if (mode == 0) {
          if (bz) v += bz[col];
          Cm[o] = v;
        } else if (mode == 1) {
          Cm[o] += v;
        } else {
          v += bz[col];
          Cm[o] += rowscale[(size_t)row * rs_stride] * v;
        }
      }
}

// ---------------------------------------------------------------------------
// Flash-style causal attention, one workgroup per (qblk64, head, batch).
// ---------------------------------------------------------------------------
__global__ __launch_bounds__(256, 2) void attn_kernel(
    const float* __restrict__ qf, const float* __restrict__ kf, const float* __restrict__ vf,
    f16* __restrict__ ohi, f16* __restrict__ olo)
{
  const int qblk = blockIdx.x, h = blockIdx.y, b = blockIdx.z;
  const int tid = threadIdx.x, wave = tid >> 6, lane = tid & 63;
  const int quad = lane >> 4, l15 = lane & 15;
  const int q0 = qblk * 64;
  const size_t bh_off = (size_t)b * 1024 * 1024 + (size_t)h * 64;

  __shared__ f16 KH[64 * 72], KL[64 * 72], VH[64 * 72], VL[64 * 72];
  __shared__ f16 PH[4][16 * 72], PL[4][16 * 72];

#pragma unroll
  for (int i = 0; i < 4; i++) {
    int idx = tid + i * 256;
    int row = idx >> 4, c4 = (idx & 15) * 4;
    float4 d = *(const float4*)&qf[bh_off + (size_t)(q0 + row) * 1024 + c4];
#pragma unroll
    for (int j = 0; j < 4; j++) {
      f16 hh, ll; split_f32(((const float*)&d)[j], hh, ll);
      KH[row * 72 + c4 + j] = hh;
      KL[row * 72 + c4 + j] = ll;
    }
  }
  __syncthreads();
  f16x8 qh[2], ql[2];
#pragma unroll
  for (int ks = 0; ks < 2; ks++) {
    qh[ks] = *(const f16x8*)&KH[(wave * 16 + l15) * 72 + ks * 32 + quad * 8];
    ql[ks] = *(const f16x8*)&KL[(wave * 16 + l15) * 72 + ks * 32 + quad * 8];
  }

  f32x4 o0[4], o1[4];
#pragma unroll
  for (int i = 0; i < 4; i++) { o0[i] = (f32x4){0.f,0.f,0.f,0.f}; o1[i] = (f32x4){0.f,0.f,0.f,0.f}; }
  float mrow[4] = {-3.0e38f, -3.0e38f, -3.0e38f, -3.0e38f};
  float lrow[4] = {0.f, 0.f, 0.f, 0.f};

  for (int kb = 0; kb <= qblk; kb++) {
    __syncthreads();
#pragma unroll
    for (int i = 0; i < 4; i++) {
      int idx = tid + i * 256;
      int row = idx >> 4, c4 = (idx & 15) * 4;
      float4 dk = *(const float4*)&kf[bh_off + (size_t)(kb * 64 + row) * 1024 + c4];
      float4 dv = *(const float4*)&vf[bh_off + (size_t)(kb * 64 + row) * 1024 + c4];
#pragma unroll
      for (int j = 0; j < 4; j++) {
        f16 hh, ll;
        split_f32(((const float*)&dk)[j], hh, ll);
        KH[row * 72 + c4 + j] = hh;  KL[row * 72 + c4 + j] = ll;
        split_f32(((const float*)&dv)[j], hh, ll);
        VH[(c4 + j) * 72 + row] = hh;  VL[(c4 + j) * 72 + row] = ll;
      }
    }
    __syncthreads();

    f32x4 s0[4], s1[4];
#pragma unroll
    for (int i = 0; i < 4; i++) { s0[i] = (f32x4){0.f,0.f,0.f,0.f}; s1[i] = (f32x4){0.f,0.f,0.f,0.f}; }
#pragma unroll
    for (int ks = 0; ks < 2; ks++) {
#pragma unroll
      for (int nt = 0; nt < 4; nt++) {
        f16x8 bhh = *(const f16x8*)&KH[(nt * 16 + l15) * 72 + ks * 32 + quad * 8];
        f16x8 bll = *(const f16x8*)&KL[(nt * 16 + l15) * 72 + ks * 32 + quad * 8];
        s0[nt] = __builtin_amdgcn_mfma_f32_16x16x32_f16(qh[ks], bhh, s0[nt], 0, 0, 0);
        s1[nt] = __builtin_amdgcn_mfma_f32_16x16x32_f16(qh[ks], bll, s1[nt], 0, 0, 0);
        s1[nt] = __builtin_amdgcn_mfma_f32_16x16x32_f16(ql[ks], bhh, s1[nt], 0, 0, 0);
      }
    }
    float sc[4][4], bm[4] = {-3.0e38f, -3.0e38f, -3.0e38f, -3.0e38f};
#pragma unroll
    for (int nt = 0; nt < 4; nt++)
#pragma unroll
      for (int r = 0; r < 4; r++) {
        float s = (s0[nt][r] + s1[nt][r] * (1.0f / 2048.0f)) * 0.125f;
        int kg = kb * 64 + nt * 16 + l15;
        int qg = q0 + wave * 16 + quad * 4 + r;
        if (kg > qg) s = -1.0e9f;
        sc[nt][r] = s;
        bm[r] = fmaxf(bm[r], s);
      }
#pragma unroll
    for (int r = 0; r < 4; r++) {
#pragma unroll
      for (int off = 1; off < 16; off <<= 1) bm[r] = fmaxf(bm[r], __shfl_xor(bm[r], off));
    }
    float alpha[4], ps[4] = {0.f, 0.f, 0.f, 0.f};
#pragma unroll
    for (int r = 0; r < 4; r++) {
      float mn = fmaxf(mrow[r], bm[r]);
      alpha[r] = expf(mrow[r] - mn);
      mrow[r] = mn;
    }
#pragma unroll
    for (int nt = 0; nt < 4; nt++)
#pragma unroll
      for (int r = 0; r < 4; r++) {
        float pv = expf(sc[nt][r] - mrow[r]);
        sc[nt][r] = pv;
        ps[r] += pv;
      }
#pragma unroll
    for (int r = 0; r < 4; r++) {
#pragma unroll
      for (int off = 1; off < 16; off <<= 1) ps[r] += __shfl_xor(ps[r], off);
      lrow[r] = lrow[r] * alpha[r] + ps[r];
    }
#pragma unroll
    for (int nt = 0; nt < 4; nt++)
#pragma unroll
      for (int r = 0; r < 4; r++) {
        f16 hh, ll; split_f32(sc[nt][r], hh, ll);
        PH[wave][(quad * 4 + r) * 72 + nt * 16 + l15] = hh;
        PL[wave][(quad * 4 + r) * 72 + nt * 16 + l15] = ll;
      }
#pragma unroll
    for (int dt = 0; dt < 4; dt++)
#pragma unroll
      for (int r = 0; r < 4; r++) { o0[dt][r] *= alpha[r]; o1[dt][r] *= alpha[r]; }
#pragma unroll
    for (int ks = 0; ks < 2; ks++) {
      f16x8 ah = *(const f16x8*)&PH[wave][l15 * 72 + ks * 32 + quad * 8];
      f16x8 al = *(const f16x8*)&PL[wave][l15 * 72 + ks * 32 + quad * 8];
#pragma unroll
      for (int dt = 0; dt < 4; dt++) {
        f16x8 bhh = *(const f16x8*)&VH[(dt * 16 + l15) * 72 + ks * 32 + quad * 8];
        f16x8 bll = *(const f16x8*)&VL[(dt * 16 + l15) * 72 + ks * 32 + quad * 8];
        o0[dt] = __builtin_amdgcn_mfma_f32_16x16x32_f16(ah, bhh, o0[dt], 0, 0, 0);
        o1[dt] = __builtin_amdgcn_mfma_f32_16x16x32_f16(ah, bll, o1[dt], 0, 0, 0);
        o1[dt] = __builtin_amdgcn_mfma_f32_16x16x32_f16(al, bhh, o1[dt], 0, 0, 0);
      }
    }
  }

#pragma unroll
  for (int dt = 0; dt < 4; dt++)
#pragma unroll
    for (int r = 0; r < 4; r++) {
      float o = (o0[dt][r] + o1[dt][r] * (1.0f / 2048.0f)) / lrow[r];
      int t = b * 1024 + q0 + wave * 16 + quad * 4 + r;
      size_t off = (size_t)t * 1024 + h * 64 + dt * 16 + l15;
      f16 hh, ll; split_f32(o, hh, ll);
      ohi[off] = hh; olo[off] = ll;
    }
}

// ---------------------------------------------------------------------------
__global__ __launch_bounds__(256) void rmsnorm_kernel(
    const float* __restrict__ x, const float* __restrict__ w,
    f16* __restrict__ ohi, f16* __restrict__ olo, float* __restrict__ of32)
{
  int t = blockIdx.x, tid = threadIdx.x;
  const float* xr = x + (size_t)t * HH;
  float4 xv = *(const float4*)&xr[tid * 4];
  float ss = xv.x * xv.x + xv.y * xv.y + xv.z * xv.z + xv.w * xv.w;
#pragma unroll
  for (int off = 32; off > 0; off >>= 1) ss += __shfl_down(ss, off);
  __shared__ float red[4];
  if ((tid & 63) == 0) red[tid >> 6] = ss;
  __syncthreads();
  float rs = 1.0f / sqrtf((red[0] + red[1] + red[2] + red[3]) * (1.0f / HH) + 1e-5f);
  float4 wv = *(const float4*)&w[tid * 4];
  float y0 = xv.x * rs * wv.x, y1 = xv.y * rs * wv.y;
  float y2 = xv.z * rs * wv.z, y3 = xv.w * rs * wv.w;
  f16 h0, l0, h1, l1, h2, l2, h3, l3;
  split_f32(y0, h0, l0); split_f32(y1, h1, l1);
  split_f32(y2, h2, l2); split_f32(y3, h3, l3);
  size_t o = (size_t)t * HH + tid * 4;
  *(f16x4*)&ohi[o] = (f16x4){h0, h1, h2, h3};
  *(f16x4*)&olo[o] = (f16x4){l0, l1, l2, l3};
  if (of32) *(float4*)&of32[o] = (float4){y0, y1, y2, y3};
}

__global__ __launch_bounds__(256) void embed_kernel(
    const int* __restrict__ ids, const float* __restrict__ emb, float* __restrict__ x)
{
  int t = blockIdx.x, tid = threadIdx.x;
  int v = ids[t];
  float4 d = *(const float4*)&emb[(size_t)v * HH + tid * 4];
  d.x *= 32.0f; d.y *= 32.0f; d.z *= 32.0f; d.w *= 32.0f;
  *(float4*)&x[(size_t)t * HH + tid * 4] = d;
}

__global__ __launch_bounds__(256) void rope_tables_kernel(float* __restrict__ cosT, float* __restrict__ sinT)
{
  int idx = blockIdx.x * 256 + threadIdx.x;   // 1024*32
  int s = idx >> 5, j = idx & 31;
  double theta = pow(10000.0, -((double)(2 * j)) / 64.0);
  double ang = (double)s * theta;
  cosT[idx] = (float)cos(ang);
  sinT[idx] = (float)sin(ang);
}

__global__ __launch_bounds__(256) void rope_kernel(
    float* __restrict__ q, float* __restrict__ k,
    const float* __restrict__ cosT, const float* __restrict__ sinT)
{
  int idx = blockIdx.x * 256 + threadIdx.x;   // NT*16*32
  int j = idx & 31, h = (idx >> 5) & 15, t = idx >> 9;
  int s = t & 1023;
  float c = cosT[s * 32 + j], sn = sinT[s * 32 + j];
  size_t base = (size_t)t * HH + h * 64 + j;
  float q1 = q[base], q2 = q[base + 32];
  q[base] = q1 * c - q2 * sn;
  q[base + 32] = q1 * sn + q2 * c;
  float k1 = k[base], k2 = k[base + 32];
  k[base] = k1 * c - k2 * sn;
  k[base + 32] = k1 * sn + k2 * c;
}

// gating in pure f32 (routing must match reference bit-for-bit in ordering)
__global__ __launch_bounds__(256) void gating_kernel(
    const float* __restrict__ h2f, const float* __restrict__ gw, const float* __restrict__ gb,
    float* __restrict__ comb, int* __restrict__ cnt)
{
  int t = blockIdx.x, tid = threadIdx.x;
  float4 xv = *(const float4*)&h2f[(size_t)t * HH + tid * 4];
  float4 w0 = *(const float4*)&gw[(size_t)(tid * 4 + 0) * 4];
  float4 w1 = *(const float4*)&gw[(size_t)(tid * 4 + 1) * 4];
  float4 w2 = *(const float4*)&gw[(size_t)(tid * 4 + 2) * 4];
  float4 w3 = *(const float4*)&gw[(size_t)(tid * 4 + 3) * 4];
  float a0 = xv.x * w0.x + xv.y * w1.x + xv.z * w2.x + xv.w * w3.x;
  float a1 = xv.x * w0.y + xv.y * w1.y + xv.z * w2.y + xv.w * w3.y;
  float a2 = xv.x * w0.z + xv.y * w1.z + xv.z * w2.z + xv.w * w3.z;
  float a3 = xv.x * w0.w + xv.y * w1.w + xv.z * w2.w + xv.w * w3.w;
#pragma unroll
  for (int off = 32; off > 0; off >>= 1) {
    a0 += __shfl_down(a0, off); a1 += __shfl_down(a1, off);
    a2 += __shfl_down(a2, off); a3 += __shfl_down(a3, off);
  }
  __shared__ float red[4][4];
  if ((tid & 63) == 0) { int w = tid >> 6; red[w][0] = a0; red[w][1] = a1; red[w][2] = a2; red[w][3] = a3; }
  __syncthreads();
  if (tid == 0) {
    float lg[4];
#pragma unroll
    for (int e = 0; e < 4; e++)
      lg[e] = red[0][e] + red[1][e] + red[2][e] + red[3][e] + gb[e];
    int e1 = 0;
    for (int e = 1; e < 4; e++) if (lg[e] > lg[e1]) e1 = e;
    int e2 = -1;
    for (int e = 0; e < 4; e++) if (e != e1 && (e2 < 0 || lg[e] > lg[e2])) e2 = e;
    float p2 = expf(lg[e2] - lg[e1]);
    float v1 = 1.0f / (1.0f + p2), v2 = p2 / (1.0f + p2);
    float c[4] = {0.f, 0.f, 0.f, 0.f};
    c[e1] = v1; c[e2] = v2;
    *(float4*)&comb[(size_t)t * 4] = (float4){c[0], c[1], c[2], c[3]};
    atomicAdd(&cnt[e1], 1);
    atomicAdd(&cnt[e2], 1);
  }
}

__global__ __launch_bounds__(256) void gelumul_kernel(
    const float* __restrict__ g, const float* __restrict__ u,
    f16* __restrict__ oh, f16* __restrict__ ol)
{
  size_t i = ((size_t)blockIdx.x * 256 + threadIdx.x) * 4;
  float4 gv = *(const float4*)&g[i];
  float4 uv = *(const float4*)&u[i];
  f16 h[4], l[4];
#pragma unroll
  for (int j = 0; j < 4; j++) {
    float xx = ((const float*)&gv)[j];
    float ge = 0.5f * xx * (1.0f + erff(xx * 0.70710678118654752f));
    float y = ge * ((const float*)&uv)[j];
    split_f32(y, h[j], l[j]);
  }
  *(f16x4*)&oh[i] = (f16x4){h[0], h[1], h[2], h[3]};
  *(f16x4*)&ol[i] = (f16x4){l[0], l[1], l[2], l[3]};
}

__global__ void zero_cnt_kernel(int* cnt) {
  if (threadIdx.x < 16) cnt[threadIdx.x] = 0;
}

__global__ void bal_kernel(const int* __restrict__ cnt, float* __restrict__ out) {
  if (threadIdx.x == 0) {
    float bal = 0.f;
    for (int l = 0; l < NL; l++)
      for (int e = 0; e < NE; e++) {
        float u = (float)cnt[l * NE + e] * (1.0f / (float)NT);
        float d = u - 0.25f;
        bal += d * d;
      }
    out[0] = bal;
  }
}

// ---------------------------------------------------------------------------
extern "C" void kernel_launch(void* const* d_in, const int* in_sizes, int n_in,
                              void* d_out, int out_size, void* d_ws, size_t ws_size,
                              hipStream_t stream)
{
  (void)in_sizes; (void)n_in; (void)out_size; (void)ws_size;
  const int*   ids  = (const int*)  d_in[0];
  const float* temb = (const float*)d_in[1];
  const float* n1w  = (const float*)d_in[2];
  const float* wq   = (const float*)d_in[3];
  const float* wk   = (const float*)d_in[4];
  const float* wv   = (const float*)d_in[5];
  const float* wo   = (const float*)d_in[6];
  const float* n2w  = (const float*)d_in[7];
  const float* gw   = (const float*)d_in[8];
  const float* gb   = (const float*)d_in[9];
  const float* egw  = (const float*)d_in[10];
  const float* egb  = (const float*)d_in[11];
  const float* euw  = (const float*)d_in[12];
  const float* eub  = (const float*)d_in[13];
  const float* edw  = (const float*)d_in[14];
  const float* edb  = (const float*)d_in[15];
  const float* nfw  = (const float*)d_in[16];
  const float* lmh  = (const float*)d_in[17];
  float* out = (float*)d_out;

  char* p = (char*)d_ws;
  auto carve = [&](size_t n) { char* r = p; p += (n + 255) & ~(size_t)255; return r; };
  float* x    = (float*)carve((size_t)NT * HH * 4);
  float* h2f  = (float*)carve((size_t)NT * HH * 4);
  f16*   hhi  = (f16*)  carve((size_t)NT * HH * 2);
  f16*   hlo  = (f16*)  carve((size_t)NT * HH * 2);
  f16*   ahi  = (f16*)  carve((size_t)NT * HH * 2);
  f16*   alo  = (f16*)  carve((size_t)NT * HH * 2);
  f16*   guh  = (f16*)  carve((size_t)NT * FFD * 2);
  f16*   gul  = (f16*)  carve((size_t)NT * FFD * 2);
  float* gbuf = (float*)carve((size_t)NT * FFD * 4);
  float* ubuf = (float*)carve((size_t)NT * FFD * 4);
  float* comb = (float*)carve((size_t)NT * NE * 4);
  int*   cnt  = (int*)  carve(64);
  float* cosT = (float*)carve((size_t)1024 * 32 * 4);
  float* sinT = (float*)carve((size_t)1024 * 32 * 4);
  // weight split/transpose buffers: max need = lm chunk 6400*1024 elems
  const size_t WB = (size_t)LMCH * HH;   // 6.55M elems
  f16* whi = (f16*)carve(WB * 2);
  f16* wlo = (f16*)carve(WB * 2);
  // q/k/v live in gbuf/ubuf (phases don't overlap within a layer)
  float* qf = gbuf;
  float* kf = gbuf + (size_t)NT * HH;
  float* vf = ubuf;

  zero_cnt_kernel<<<1, 64, 0, stream>>>(cnt);
  rope_tables_kernel<<<128, 256, 0, stream>>>(cosT, sinT);
  embed_kernel<<<NT, 256, 0, stream>>>(ids, temb, x);

  for (int l = 0; l < NL; l++) {
    rmsnorm_kernel<<<NT, 256, 0, stream>>>(x, n1w + (size_t)l * HH, hhi, hlo, nullptr);
    // pre-split QKV weights -> [N][K] f16 hi/lo
    wsplit_kernel<<<dim3(HH/32, HH/32), 256, 0, stream>>>(wq + (size_t)l * HH * HH, HH, whi, wlo, HH);
    wsplit_kernel<<<dim3(HH/32, HH/32), 256, 0, stream>>>(wk + (size_t)l * HH * HH, HH, whi + (size_t)HH*HH, wlo + (size_t)HH*HH, HH);
    wsplit_kernel<<<dim3(HH/32, HH/32), 256, 0, stream>>>(wv + (size_t)l * HH * HH, HH, whi + (size_t)2*HH*HH, wlo + (size_t)2*HH*HH, HH);
    gemm_split<<<dim3(8, 16, 3), 256, 0, stream>>>(hhi, hlo,
        whi, wlo, (unsigned long long)HH * HH,
        qf, kf, vf, nullptr, nullptr, nullptr, nullptr, 0, NT, HH, HH, HH, 0);
    rope_kernel<<<4096, 256, 0, stream>>>(qf, kf, cosT, sinT);
    attn_kernel<<<dim3(16, 16, 2), 256, 0, stream>>>(qf, kf, vf, ahi, alo);
    wsplit_kernel<<<dim3(HH/32, HH/32), 256, 0, stream>>>(wo + (size_t)l * HH * HH, HH, whi, wlo, HH);
    gemm_split<<<dim3(8, 16, 1), 256, 0, stream>>>(ahi, alo,
        whi, wlo, 0,
        x, nullptr, nullptr, nullptr, nullptr, nullptr, nullptr, 0, NT, HH, HH, HH, 1);
    rmsnorm_kernel<<<NT, 256, 0, stream>>>(x, n2w + (size_t)l * HH, hhi, hlo, h2f);
    gating_kernel<<<NT, 256, 0, stream>>>(h2f, gw + (size_t)l * HH * NE, gb + (size_t)l * NE,
                                          comb, cnt + l * NE);
    for (int e = 0; e < NE; e++) {
      size_t wof = ((size_t)(l * NE + e)) * HH * FFD;
      size_t bof = (size_t)(l * NE + e) * FFD;
      // gate + up weights fused (z=2)
      wsplit_kernel<<<dim3(FFD/32, HH/32), 256, 0, stream>>>(egw + wof, FFD, whi, wlo, HH);
      wsplit_kernel<<<dim3(FFD/32, HH/32), 256, 0, stream>>>(euw + wof, FFD, whi + (size_t)HH*FFD, wlo + (size_t)HH*FFD, HH);
      gemm_split<<<dim3(20, 16, 2), 256, 0, stream>>>(hhi, hlo,
          whi, wlo, (unsigned long long)HH * FFD,
          gbuf, ubuf, nullptr,
          egb + bof, eub + bof, nullptr, nullptr, 0, NT, FFD, HH, FFD, 0);
      gelumul_kernel<<<(NT * FFD / 1024), 256, 0, stream>>>(gbuf, ubuf, guh, gul);
      // down-proj
      wsplit_kernel<<<dim3(HH/32, FFD/32), 256, 0, stream>>>(edw + wof, HH, whi, wlo, FFD);
      gemm_split<<<dim3(8, 16, 1), 256, 0, stream>>>(guh, gul,
          whi, wlo, 0,
          x, nullptr, nullptr,
          edb + (size_t)(l * NE + e) * HH, nullptr, nullptr, comb + e, NE, NT, HH, FFD, HH, 2);
    }
  }
  rmsnorm_kernel<<<NT, 256, 0, stream>>>(x, nfw, hhi, hlo, nullptr);
  // lm_head in 5 column chunks of 6400 (keeps the split buffer small)
  for (int ch = 0; ch < 5; ch++) {
    wsplit_kernel<<<dim3(LMCH/32, HH/32), 256, 0, stream>>>(lmh + (size_t)ch * LMCH, NV, whi, wlo, HH);
    gemm_split<<<dim3(LMCH/128, 16, 1), 256, 0, stream>>>(hhi, hlo,
        whi, wlo, 0,
        out + (size_t)ch * LMCH, nullptr, nullptr,
        nullptr, nullptr, nullptr, nullptr, 0, NT, LMCH, HH, NV, 0);
  }
  bal_kernel<<<1, 64, 0, stream>>>(cnt, out + (size_t)NT * NV);
}

// Round 2
// 6018.877 us; speedup vs baseline: 2.2377x; 1.0650x over previous
//
#include <hip/hip_runtime.h>
#include <math.h>

// ---------------------------------------------------------------------------
// ChatModel forward on MI355X.
// Precision strategy: all big GEMMs use f16x2 "split" MFMA:
//   x = hi + lo/2048   (lo stored pre-scaled by 2048 -> stays fp16-normal)
//   B (weights ~0.02) additionally pre-scaled by 256.
//   D = acc_hh/256 + acc_cross/(256*2048); 3 mfma per fragment pair.
// Weights pre-split + pre-transposed once per use by wsplit_kernel.
// This round: top-2 sparse MoE — gating builds per-expert token lists;
// expert GEMMs gather A rows / scatter C rows and early-exit past the
// per-expert count (device-side count read, no host sync).
// ---------------------------------------------------------------------------

typedef _Float16 f16;
typedef _Float16 f16x8 __attribute__((ext_vector_type(8)));
typedef _Float16 f16x4 __attribute__((ext_vector_type(4)));
typedef float f32x4 __attribute__((ext_vector_type(4)));

#define NT 2048      // B*S tokens
#define HH 1024      // hidden
#define NHEAD 16
#define HDIM 64
#define NL 4
#define FFD 2560
#define NE 4
#define NV 32000
#define LMCH 6400    // lm_head column chunk (5 chunks of 6400 = 32000)

__device__ __forceinline__ void split_f32(float x, f16& h, f16& l) {
  h = (f16)x;
  l = (f16)((x - (float)h) * 2048.0f);
}

// ---------------------------------------------------------------------------
// Weight pre-pass: B[K][N] f32 (row stride ldb) -> BT hi/lo [N][K] f16,
// scaled by 256 and split. Tiled 32x32 transpose through LDS.
// grid: (N/32, K/32), block 256.
// ---------------------------------------------------------------------------
__global__ __launch_bounds__(256) void wsplit_kernel(
    const float* __restrict__ B, int ldb,
    f16* __restrict__ th, f16* __restrict__ tl, int K)
{
  __shared__ float t[32][33];
  const int bn = blockIdx.x * 32, bk = blockIdx.y * 32;
  const int c = threadIdx.x & 31, r0 = (threadIdx.x >> 5) * 4;
#pragma unroll
  for (int i = 0; i < 4; i++)
    t[r0 + i][c] = B[(size_t)(bk + r0 + i) * ldb + bn + c];
  __syncthreads();
#pragma unroll
  for (int i = 0; i < 4; i++) {
    int n = r0 + i;
    float v = t[c][n] * 256.0f;
    f16 h = (f16)v;
    f16 l = (f16)((v - (float)h) * 2048.0f);
    size_t o = (size_t)(bn + n) * K + bk + c;
    th[o] = h; tl[o] = l;
  }
}

// ---------------------------------------------------------------------------
// Split-precision GEMM: C[M,N] = A[M,K] (split f16 hi/lo) * B^T[N,K] (split).
// blockIdx.z selects weight (Bh + z*bstride) and C/bias pointer.
// mode 0: C = v (+bias)   mode 1: C += v   mode 2: C += rowscale[orow]*(v+bias)
// Sparse-MoE support:
//   cntp  : if non-null, device count; blocks with m0 >= *cntp exit; row
//           writes guarded by row < cnt.
//   gidxA : if non-null, A row gather indices (gathered input).
//   gidxC : if non-null, C row scatter indices (and rowscale row).
// ---------------------------------------------------------------------------
#define BM 128
#define BN 128
#define BK 32
#define LDP 40   // padded LDS leading dim (f16 elems); 80B row stride, 16B-aligned

__global__ __launch_bounds__(256, 2) void gemm_split(
    const f16* __restrict__ Ahi, const f16* __restrict__ Alo,
    const f16* __restrict__ Bh, const f16* __restrict__ Bl,
    unsigned long long bstride,
    float* __restrict__ C0, float* __restrict__ C1, float* __restrict__ C2,
    const float* __restrict__ bias0, const float* __restrict__ bias1,
    const float* __restrict__ bias2,
    const float* __restrict__ rowscale, int rs_stride,
    const int* __restrict__ gidxA, const int* __restrict__ gidxC,
    const int* __restrict__ cntp,
    int M, int N, int K, int ldc, int mode)
{
  const int m0 = blockIdx.y * BM, n0 = blockIdx.x * BN;
  int cnt = M;
  if (cntp) cnt = *cntp;
  if (m0 >= cnt) return;

  const int z = blockIdx.z;
  const f16* Bhz = Bh + (size_t)z * bstride;
  const f16* Blz = Bl + (size_t)z * bstride;
  float* Cm = (z == 0) ? C0 : (z == 1 ? C1 : C2);
  const float* bz = (z == 0) ? bias0 : (z == 1 ? bias1 : bias2);

  __shared__ f16 AsH[BM * LDP], AsL[BM * LDP], BsH[BN * LDP], BsL[BN * LDP];

  const int tid = threadIdx.x;
  const int wave = tid >> 6, lane = tid & 63, quad = lane >> 4, l15 = lane & 15;
  const int wm = (wave >> 1) * 64, wn = (wave & 1) * 64;

  // per-thread staging coordinates (fixed across k-iters); A rows may gather
  size_t arow[2], brow[2];
  int scol[2];
#pragma unroll
  for (int i = 0; i < 2; i++) {
    int idx = tid + i * 256;              // 0..511 chunks of 8 f16
    int row = idx >> 2;
    scol[i] = (idx & 3) * 8;
    int gr = m0 + row;
    if (gidxA) gr = gidxA[gr < cnt ? gr : cnt - 1];
    arow[i] = (size_t)gr * K;
    brow[i] = (size_t)(n0 + row) * K;
  }

  f32x4 acc0[4][4], acc1[4][4];
#pragma unroll
  for (int i = 0; i < 4; i++)
#pragma unroll
    for (int j = 0; j < 4; j++) {
      acc0[i][j] = (f32x4){0.f, 0.f, 0.f, 0.f};
      acc1[i][j] = (f32x4){0.f, 0.f, 0.f, 0.f};
    }

  for (int kt = 0; kt < K; kt += BK) {
#pragma unroll
    for (int i = 0; i < 2; i++) {
      int idx = tid + i * 256;
      int row = idx >> 2, col = scol[i];
      size_t ga = arow[i] + kt + col;
      *(uint4*)&AsH[row * LDP + col] = *(const uint4*)&Ahi[ga];
      *(uint4*)&AsL[row * LDP + col] = *(const uint4*)&Alo[ga];
      size_t gb = brow[i] + kt + col;
      *(uint4*)&BsH[row * LDP + col] = *(const uint4*)&Bhz[gb];
      *(uint4*)&BsL[row * LDP + col] = *(const uint4*)&Blz[gb];
    }
    __syncthreads();

    f16x8 bh[4], bl[4];
#pragma unroll
    for (int in = 0; in < 4; in++) {
      int r = wn + in * 16 + l15;
      bh[in] = *(const f16x8*)&BsH[r * LDP + quad * 8];
      bl[in] = *(const f16x8*)&BsL[r * LDP + quad * 8];
    }
#pragma unroll
    for (int im = 0; im < 4; im++) {
      int r = wm + im * 16 + l15;
      f16x8 ah = *(const f16x8*)&AsH[r * LDP + quad * 8];
      f16x8 al = *(const f16x8*)&AsL[r * LDP + quad * 8];
#pragma unroll
      for (int in = 0; in < 4; in++) {
        acc0[im][in] = __builtin_amdgcn_mfma_f32_16x16x32_f16(ah, bh[in], acc0[im][in], 0, 0, 0);
        acc1[im][in] = __builtin_amdgcn_mfma_f32_16x16x32_f16(ah, bl[in], acc1[im][in], 0, 0, 0);
        acc1[im][in] = __builtin_amdgcn_mfma_f32_16x16x32_f16(al, bh[in], acc1[im][in], 0, 0, 0);
      }
    }
    __syncthreads();
  }

  const float inv0 = 1.0f / 256.0f, inv1 = 1.0f / (256.0f * 2048.0f);
#pragma unroll
  for (int im = 0; im < 4; im++)
#pragma unroll
    for (int in = 0; in < 4; in++)
#pragma unroll
      for (int r = 0; r < 4; r++) {
        int grow = m0 + wm + im * 16 + quad * 4 + r;
        if (grow >= cnt) continue;
        int orow = gidxC ? gidxC[grow] : grow;
        int col = n0 + wn + in * 16 + l15;
        float v = acc0[im][in][r] * inv0 + acc1[im][in][r] * inv1;
        size_t o = (size_t)orow * ldc + col;
        if (mode == 0) {
          if (bz) v += bz[col];
          Cm[o] = v;
        } else if (mode == 1) {
          Cm[o] += v;
        } else {
          v += bz[col];
          Cm[o] += rowscale[(size_t)orow * rs_stride] * v;
        }
      }
}

// ---------------------------------------------------------------------------
// Flash-style causal attention, one workgroup per (qblk64, head, batch).
// ---------------------------------------------------------------------------
__global__ __launch_bounds__(256, 2) void attn_kernel(
    const float* __restrict__ qf, const float* __restrict__ kf, const float* __restrict__ vf,
    f16* __restrict__ ohi, f16* __restrict__ olo)
{
  const int qblk = blockIdx.x, h = blockIdx.y, b = blockIdx.z;
  const int tid = threadIdx.x, wave = tid >> 6, lane = tid & 63;
  const int quad = lane >> 4, l15 = lane & 15;
  const int q0 = qblk * 64;
  const size_t bh_off = (size_t)b * 1024 * 1024 + (size_t)h * 64;

  __shared__ f16 KH[64 * 72], KL[64 * 72], VH[64 * 72], VL[64 * 72];
  __shared__ f16 PH[4][16 * 72], PL[4][16 * 72];

#pragma unroll
  for (int i = 0; i < 4; i++) {
    int idx = tid + i * 256;
    int row = idx >> 4, c4 = (idx & 15) * 4;
    float4 d = *(const float4*)&qf[bh_off + (size_t)(q0 + row) * 1024 + c4];
#pragma unroll
    for (int j = 0; j < 4; j++) {
      f16 hh, ll; split_f32(((const float*)&d)[j], hh, ll);
      KH[row * 72 + c4 + j] = hh;
      KL[row * 72 + c4 + j] = ll;
    }
  }
  __syncthreads();
  f16x8 qh[2], ql[2];
#pragma unroll
  for (int ks = 0; ks < 2; ks++) {
    qh[ks] = *(const f16x8*)&KH[(wave * 16 + l15) * 72 + ks * 32 + quad * 8];
    ql[ks] = *(const f16x8*)&KL[(wave * 16 + l15) * 72 + ks * 32 + quad * 8];
  }

  f32x4 o0[4], o1[4];
#pragma unroll
  for (int i = 0; i < 4; i++) { o0[i] = (f32x4){0.f,0.f,0.f,0.f}; o1[i] = (f32x4){0.f,0.f,0.f,0.f}; }
  float mrow[4] = {-3.0e38f, -3.0e38f, -3.0e38f, -3.0e38f};
  float lrow[4] = {0.f, 0.f, 0.f, 0.f};

  for (int kb = 0; kb <= qblk; kb++) {
    __syncthreads();
#pragma unroll
    for (int i = 0; i < 4; i++) {
      int idx = tid + i * 256;
      int row = idx >> 4, c4 = (idx & 15) * 4;
      float4 dk = *(const float4*)&kf[bh_off + (size_t)(kb * 64 + row) * 1024 + c4];
      float4 dv = *(const float4*)&vf[bh_off + (size_t)(kb * 64 + row) * 1024 + c4];
#pragma unroll
      for (int j = 0; j < 4; j++) {
        f16 hh, ll;
        split_f32(((const float*)&dk)[j], hh, ll);
        KH[row * 72 + c4 + j] = hh;  KL[row * 72 + c4 + j] = ll;
        split_f32(((const float*)&dv)[j], hh, ll);
        VH[(c4 + j) * 72 + row] = hh;  VL[(c4 + j) * 72 + row] = ll;
      }
    }
    __syncthreads();

    f32x4 s0[4], s1[4];
#pragma unroll
    for (int i = 0; i < 4; i++) { s0[i] = (f32x4){0.f,0.f,0.f,0.f}; s1[i] = (f32x4){0.f,0.f,0.f,0.f}; }
#pragma unroll
    for (int ks = 0; ks < 2; ks++) {
#pragma unroll
      for (int nt = 0; nt < 4; nt++) {
        f16x8 bhh = *(const f16x8*)&KH[(nt * 16 + l15) * 72 + ks * 32 + quad * 8];
        f16x8 bll = *(const f16x8*)&KL[(nt * 16 + l15) * 72 + ks * 32 + quad * 8];
        s0[nt] = __builtin_amdgcn_mfma_f32_16x16x32_f16(qh[ks], bhh, s0[nt], 0, 0, 0);
        s1[nt] = __builtin_amdgcn_mfma_f32_16x16x32_f16(qh[ks], bll, s1[nt], 0, 0, 0);
        s1[nt] = __builtin_amdgcn_mfma_f32_16x16x32_f16(ql[ks], bhh, s1[nt], 0, 0, 0);
      }
    }
    float sc[4][4], bm[4] = {-3.0e38f, -3.0e38f, -3.0e38f, -3.0e38f};
#pragma unroll
    for (int nt = 0; nt < 4; nt++)
#pragma unroll
      for (int r = 0; r < 4; r++) {
        float s = (s0[nt][r] + s1[nt][r] * (1.0f / 2048.0f)) * 0.125f;
        int kg = kb * 64 + nt * 16 + l15;
        int qg = q0 + wave * 16 + quad * 4 + r;
        if (kg > qg) s = -1.0e9f;
        sc[nt][r] = s;
        bm[r] = fmaxf(bm[r], s);
      }
#pragma unroll
    for (int r = 0; r < 4; r++) {
#pragma unroll
      for (int off = 1; off < 16; off <<= 1) bm[r] = fmaxf(bm[r], __shfl_xor(bm[r], off));
    }
    float alpha[4], ps[4] = {0.f, 0.f, 0.f, 0.f};
#pragma unroll
    for (int r = 0; r < 4; r++) {
      float mn = fmaxf(mrow[r], bm[r]);
      alpha[r] = expf(mrow[r] - mn);
      mrow[r] = mn;
    }
#pragma unroll
    for (int nt = 0; nt < 4; nt++)
#pragma unroll
      for (int r = 0; r < 4; r++) {
        float pv = expf(sc[nt][r] - mrow[r]);
        sc[nt][r] = pv;
        ps[r] += pv;
      }
#pragma unroll
    for (int r = 0; r < 4; r++) {
#pragma unroll
      for (int off = 1; off < 16; off <<= 1) ps[r] += __shfl_xor(ps[r], off);
      lrow[r] = lrow[r] * alpha[r] + ps[r];
    }
#pragma unroll
    for (int nt = 0; nt < 4; nt++)
#pragma unroll
      for (int r = 0; r < 4; r++) {
        f16 hh, ll; split_f32(sc[nt][r], hh, ll);
        PH[wave][(quad * 4 + r) * 72 + nt * 16 + l15] = hh;
        PL[wave][(quad * 4 + r) * 72 + nt * 16 + l15] = ll;
      }
#pragma unroll
    for (int dt = 0; dt < 4; dt++)
#pragma unroll
      for (int r = 0; r < 4; r++) { o0[dt][r] *= alpha[r]; o1[dt][r] *= alpha[r]; }
#pragma unroll
    for (int ks = 0; ks < 2; ks++) {
      f16x8 ah = *(const f16x8*)&PH[wave][l15 * 72 + ks * 32 + quad * 8];
      f16x8 al = *(const f16x8*)&PL[wave][l15 * 72 + ks * 32 + quad * 8];
#pragma unroll
      for (int dt = 0; dt < 4; dt++) {
        f16x8 bhh = *(const f16x8*)&VH[(dt * 16 + l15) * 72 + ks * 32 + quad * 8];
        f16x8 bll = *(const f16x8*)&VL[(dt * 16 + l15) * 72 + ks * 32 + quad * 8];
        o0[dt] = __builtin_amdgcn_mfma_f32_16x16x32_f16(ah, bhh, o0[dt], 0, 0, 0);
        o1[dt] = __builtin_amdgcn_mfma_f32_16x16x32_f16(ah, bll, o1[dt], 0, 0, 0);
        o1[dt] = __builtin_amdgcn_mfma_f32_16x16x32_f16(al, bhh, o1[dt], 0, 0, 0);
      }
    }
  }

#pragma unroll
  for (int dt = 0; dt < 4; dt++)
#pragma unroll
    for (int r = 0; r < 4; r++) {
      float o = (o0[dt][r] + o1[dt][r] * (1.0f / 2048.0f)) / lrow[r];
      int t = b * 1024 + q0 + wave * 16 + quad * 4 + r;
      size_t off = (size_t)t * 1024 + h * 64 + dt * 16 + l15;
      f16 hh, ll; split_f32(o, hh, ll);
      ohi[off] = hh; olo[off] = ll;
    }
}

// ---------------------------------------------------------------------------
__global__ __launch_bounds__(256) void rmsnorm_kernel(
    const float* __restrict__ x, const float* __restrict__ w,
    f16* __restrict__ ohi, f16* __restrict__ olo, float* __restrict__ of32)
{
  int t = blockIdx.x, tid = threadIdx.x;
  const float* xr = x + (size_t)t * HH;
  float4 xv = *(const float4*)&xr[tid * 4];
  float ss = xv.x * xv.x + xv.y * xv.y + xv.z * xv.z + xv.w * xv.w;
#pragma unroll
  for (int off = 32; off > 0; off >>= 1) ss += __shfl_down(ss, off);
  __shared__ float red[4];
  if ((tid & 63) == 0) red[tid >> 6] = ss;
  __syncthreads();
  float rs = 1.0f / sqrtf((red[0] + red[1] + red[2] + red[3]) * (1.0f / HH) + 1e-5f);
  float4 wv = *(const float4*)&w[tid * 4];
  float y0 = xv.x * rs * wv.x, y1 = xv.y * rs * wv.y;
  float y2 = xv.z * rs * wv.z, y3 = xv.w * rs * wv.w;
  f16 h0, l0, h1, l1, h2, l2, h3, l3;
  split_f32(y0, h0, l0); split_f32(y1, h1, l1);
  split_f32(y2, h2, l2); split_f32(y3, h3, l3);
  size_t o = (size_t)t * HH + tid * 4;
  *(f16x4*)&ohi[o] = (f16x4){h0, h1, h2, h3};
  *(f16x4*)&olo[o] = (f16x4){l0, l1, l2, l3};
  if (of32) *(float4*)&of32[o] = (float4){y0, y1, y2, y3};
}

__global__ __launch_bounds__(256) void embed_kernel(
    const int* __restrict__ ids, const float* __restrict__ emb, float* __restrict__ x)
{
  int t = blockIdx.x, tid = threadIdx.x;
  int v = ids[t];
  float4 d = *(const float4*)&emb[(size_t)v * HH + tid * 4];
  d.x *= 32.0f; d.y *= 32.0f; d.z *= 32.0f; d.w *= 32.0f;
  *(float4*)&x[(size_t)t * HH + tid * 4] = d;
}

__global__ __launch_bounds__(256) void rope_tables_kernel(float* __restrict__ cosT, float* __restrict__ sinT)
{
  int idx = blockIdx.x * 256 + threadIdx.x;   // 1024*32
  int s = idx >> 5, j = idx & 31;
  double theta = pow(10000.0, -((double)(2 * j)) / 64.0);
  double ang = (double)s * theta;
  cosT[idx] = (float)cos(ang);
  sinT[idx] = (float)sin(ang);
}

__global__ __launch_bounds__(256) void rope_kernel(
    float* __restrict__ q, float* __restrict__ k,
    const float* __restrict__ cosT, const float* __restrict__ sinT)
{
  int idx = blockIdx.x * 256 + threadIdx.x;   // NT*16*32
  int j = idx & 31, h = (idx >> 5) & 15, t = idx >> 9;
  int s = t & 1023;
  float c = cosT[s * 32 + j], sn = sinT[s * 32 + j];
  size_t base = (size_t)t * HH + h * 64 + j;
  float q1 = q[base], q2 = q[base + 32];
  q[base] = q1 * c - q2 * sn;
  q[base + 32] = q1 * sn + q2 * c;
  float k1 = k[base], k2 = k[base + 32];
  k[base] = k1 * c - k2 * sn;
  k[base + 32] = k1 * sn + k2 * c;
}

// gating in pure f32 (routing must match reference bit-for-bit in ordering);
// also builds per-expert token lists for sparse expert GEMMs.
__global__ __launch_bounds__(256) void gating_kernel(
    const float* __restrict__ h2f, const float* __restrict__ gw, const float* __restrict__ gb,
    float* __restrict__ comb, int* __restrict__ cnt,
    int* __restrict__ elist, int* __restrict__ ecnt)
{
  int t = blockIdx.x, tid = threadIdx.x;
  float4 xv = *(const float4*)&h2f[(size_t)t * HH + tid * 4];
  float4 w0 = *(const float4*)&gw[(size_t)(tid * 4 + 0) * 4];
  float4 w1 = *(const float4*)&gw[(size_t)(tid * 4 + 1) * 4];
  float4 w2 = *(const float4*)&gw[(size_t)(tid * 4 + 2) * 4];
  float4 w3 = *(const float4*)&gw[(size_t)(tid * 4 + 3) * 4];
  float a0 = xv.x * w0.x + xv.y * w1.x + xv.z * w2.x + xv.w * w3.x;
  float a1 = xv.x * w0.y + xv.y * w1.y + xv.z * w2.y + xv.w * w3.y;
  float a2 = xv.x * w0.z + xv.y * w1.z + xv.z * w2.z + xv.w * w3.z;
  float a3 = xv.x * w0.w + xv.y * w1.w + xv.z * w2.w + xv.w * w3.w;
#pragma unroll
  for (int off = 32; off > 0; off >>= 1) {
    a0 += __shfl_down(a0, off); a1 += __shfl_down(a1, off);
    a2 += __shfl_down(a2, off); a3 += __shfl_down(a3, off);
  }
  __shared__ float red[4][4];
  if ((tid & 63) == 0) { int w = tid >> 6; red[w][0] = a0; red[w][1] = a1; red[w][2] = a2; red[w][3] = a3; }
  __syncthreads();
  if (tid == 0) {
    float lg[4];
#pragma unroll
    for (int e = 0; e < 4; e++)
      lg[e] = red[0][e] + red[1][e] + red[2][e] + red[3][e] + gb[e];
    int e1 = 0;
    for (int e = 1; e < 4; e++) if (lg[e] > lg[e1]) e1 = e;
    int e2 = -1;
    for (int e = 0; e < 4; e++) if (e != e1 && (e2 < 0 || lg[e] > lg[e2])) e2 = e;
    float p2 = expf(lg[e2] - lg[e1]);
    float v1 = 1.0f / (1.0f + p2), v2 = p2 / (1.0f + p2);
    float c[4] = {0.f, 0.f, 0.f, 0.f};
    c[e1] = v1; c[e2] = v2;
    *(float4*)&comb[(size_t)t * 4] = (float4){c[0], c[1], c[2], c[3]};
    atomicAdd(&cnt[e1], 1);
    atomicAdd(&cnt[e2], 1);
    int p1 = atomicAdd(&ecnt[e1], 1);
    elist[e1 * NT + p1] = t;
    int pq = atomicAdd(&ecnt[e2], 1);
    elist[e2 * NT + pq] = t;
  }
}

__global__ __launch_bounds__(256) void gelumul_kernel(
    const float* __restrict__ g, const float* __restrict__ u,
    f16* __restrict__ oh, f16* __restrict__ ol, const int* __restrict__ cntp)
{
  size_t i = ((size_t)blockIdx.x * 256 + threadIdx.x) * 4;
  if (cntp && i >= (size_t)(*cntp) * FFD) return;
  float4 gv = *(const float4*)&g[i];
  float4 uv = *(const float4*)&u[i];
  f16 h[4], l[4];
#pragma unroll
  for (int j = 0; j < 4; j++) {
    float xx = ((const float*)&gv)[j];
    float ge = 0.5f * xx * (1.0f + erff(xx * 0.70710678118654752f));
    float y = ge * ((const float*)&uv)[j];
    split_f32(y, h[j], l[j]);
  }
  *(f16x4*)&oh[i] = (f16x4){h[0], h[1], h[2], h[3]};
  *(f16x4*)&ol[i] = (f16x4){l[0], l[1], l[2], l[3]};
}

__global__ void zero_cnt_kernel(int* cnt) {
  if (threadIdx.x < 16) cnt[threadIdx.x] = 0;
}

__global__ void bal_kernel(const int* __restrict__ cnt, float* __restrict__ out) {
  if (threadIdx.x == 0) {
    float bal = 0.f;
    for (int l = 0; l < NL; l++)
      for (int e = 0; e < NE; e++) {
        float u = (float)cnt[l * NE + e] * (1.0f / (float)NT);
        float d = u - 0.25f;
        bal += d * d;
      }
    out[0] = bal;
  }
}

// ---------------------------------------------------------------------------
extern "C" void kernel_launch(void* const* d_in, const int* in_sizes, int n_in,
                              void* d_out, int out_size, void* d_ws, size_t ws_size,
                              hipStream_t stream)
{
  (void)in_sizes; (void)n_in; (void)out_size; (void)ws_size;
  const int*   ids  = (const int*)  d_in[0];
  const float* temb = (const float*)d_in[1];
  const float* n1w  = (const float*)d_in[2];
  const float* wq   = (const float*)d_in[3];
  const float* wk   = (const float*)d_in[4];
  const float* wv   = (const float*)d_in[5];
  const float* wo   = (const float*)d_in[6];
  const float* n2w  = (const float*)d_in[7];
  const float* gw   = (const float*)d_in[8];
  const float* gb   = (const float*)d_in[9];
  const float* egw  = (const float*)d_in[10];
  const float* egb  = (const float*)d_in[11];
  const float* euw  = (const float*)d_in[12];
  const float* eub  = (const float*)d_in[13];
  const float* edw  = (const float*)d_in[14];
  const float* edb  = (const float*)d_in[15];
  const float* nfw  = (const float*)d_in[16];
  const float* lmh  = (const float*)d_in[17];
  float* out = (float*)d_out;

  char* p = (char*)d_ws;
  auto carve = [&](size_t n) { char* r = p; p += (n + 255) & ~(size_t)255; return r; };
  float* x    = (float*)carve((size_t)NT * HH * 4);
  float* h2f  = (float*)carve((size_t)NT * HH * 4);
  f16*   hhi  = (f16*)  carve((size_t)NT * HH * 2);
  f16*   hlo  = (f16*)  carve((size_t)NT * HH * 2);
  f16*   ahi  = (f16*)  carve((size_t)NT * HH * 2);
  f16*   alo  = (f16*)  carve((size_t)NT * HH * 2);
  f16*   guh  = (f16*)  carve((size_t)NT * FFD * 2);
  f16*   gul  = (f16*)  carve((size_t)NT * FFD * 2);
  float* gbuf = (float*)carve((size_t)NT * FFD * 4);
  float* ubuf = (float*)carve((size_t)NT * FFD * 4);
  float* comb = (float*)carve((size_t)NT * NE * 4);
  int*   cnt  = (int*)  carve(64);
  int*   elist= (int*)  carve((size_t)NE * NT * 4);
  int*   ecnt = (int*)  carve(64);
  float* cosT = (float*)carve((size_t)1024 * 32 * 4);
  float* sinT = (float*)carve((size_t)1024 * 32 * 4);
  // weight split/transpose buffers: max need = lm chunk 6400*1024 elems
  const size_t WB = (size_t)LMCH * HH;   // 6.55M elems
  f16* whi = (f16*)carve(WB * 2);
  f16* wlo = (f16*)carve(WB * 2);
  // q/k/v live in gbuf/ubuf (phases don't overlap within a layer)
  float* qf = gbuf;
  float* kf = gbuf + (size_t)NT * HH;
  float* vf = ubuf;

  zero_cnt_kernel<<<1, 64, 0, stream>>>(cnt);
  rope_tables_kernel<<<128, 256, 0, stream>>>(cosT, sinT);
  embed_kernel<<<NT, 256, 0, stream>>>(ids, temb, x);

  for (int l = 0; l < NL; l++) {
    rmsnorm_kernel<<<NT, 256, 0, stream>>>(x, n1w + (size_t)l * HH, hhi, hlo, nullptr);
    // pre-split QKV weights -> [N][K] f16 hi/lo
    wsplit_kernel<<<dim3(HH/32, HH/32), 256, 0, stream>>>(wq + (size_t)l * HH * HH, HH, whi, wlo, HH);
    wsplit_kernel<<<dim3(HH/32, HH/32), 256, 0, stream>>>(wk + (size_t)l * HH * HH, HH, whi + (size_t)HH*HH, wlo + (size_t)HH*HH, HH);
    wsplit_kernel<<<dim3(HH/32, HH/32), 256, 0, stream>>>(wv + (size_t)l * HH * HH, HH, whi + (size_t)2*HH*HH, wlo + (size_t)2*HH*HH, HH);
    gemm_split<<<dim3(8, 16, 3), 256, 0, stream>>>(hhi, hlo,
        whi, wlo, (unsigned long long)HH * HH,
        qf, kf, vf, nullptr, nullptr, nullptr, nullptr, 0,
        nullptr, nullptr, nullptr, NT, HH, HH, HH, 0);
    rope_kernel<<<4096, 256, 0, stream>>>(qf, kf, cosT, sinT);
    attn_kernel<<<dim3(16, 16, 2), 256, 0, stream>>>(qf, kf, vf, ahi, alo);
    wsplit_kernel<<<dim3(HH/32, HH/32), 256, 0, stream>>>(wo + (size_t)l * HH * HH, HH, whi, wlo, HH);
    gemm_split<<<dim3(8, 16, 1), 256, 0, stream>>>(ahi, alo,
        whi, wlo, 0,
        x, nullptr, nullptr, nullptr, nullptr, nullptr, nullptr, 0,
        nullptr, nullptr, nullptr, NT, HH, HH, HH, 1);
    rmsnorm_kernel<<<NT, 256, 0, stream>>>(x, n2w + (size_t)l * HH, hhi, hlo, h2f);
    zero_cnt_kernel<<<1, 64, 0, stream>>>(ecnt);
    gating_kernel<<<NT, 256, 0, stream>>>(h2f, gw + (size_t)l * HH * NE, gb + (size_t)l * NE,
                                          comb, cnt + l * NE, elist, ecnt);
    for (int e = 0; e < NE; e++) {
      size_t wof = ((size_t)(l * NE + e)) * HH * FFD;
      size_t bof = (size_t)(l * NE + e) * FFD;
      // gate + up weights fused (z=2); A rows gathered via elist[e]
      wsplit_kernel<<<dim3(FFD/32, HH/32), 256, 0, stream>>>(egw + wof, FFD, whi, wlo, HH);
      wsplit_kernel<<<dim3(FFD/32, HH/32), 256, 0, stream>>>(euw + wof, FFD, whi + (size_t)HH*FFD, wlo + (size_t)HH*FFD, HH);
      gemm_split<<<dim3(20, 16, 2), 256, 0, stream>>>(hhi, hlo,
          whi, wlo, (unsigned long long)HH * FFD,
          gbuf, ubuf, nullptr,
          egb + bof, eub + bof, nullptr, nullptr, 0,
          elist + e * NT, nullptr, ecnt + e, NT, FFD, HH, FFD, 0);
      gelumul_kernel<<<(NT * FFD / 1024), 256, 0, stream>>>(gbuf, ubuf, guh, gul, ecnt + e);
      // down-proj: compact A rows, scatter to x with comb scaling
      wsplit_kernel<<<dim3(HH/32, FFD/32), 256, 0, stream>>>(edw + wof, HH, whi, wlo, FFD);
      gemm_split<<<dim3(8, 16, 1), 256, 0, stream>>>(guh, gul,
          whi, wlo, 0,
          x, nullptr, nullptr,
          edb + (size_t)(l * NE + e) * HH, nullptr, nullptr, comb + e, NE,
          nullptr, elist + e * NT, ecnt + e, NT, HH, FFD, HH, 2);
    }
  }
  rmsnorm_kernel<<<NT, 256, 0, stream>>>(x, nfw, hhi, hlo, nullptr);
  // lm_head in 5 column chunks of 6400 (keeps the split buffer small)
  for (int ch = 0; ch < 5; ch++) {
    wsplit_kernel<<<dim3(LMCH/32, HH/32), 256, 0, stream>>>(lmh + (size_t)ch * LMCH, NV, whi, wlo, HH);
    gemm_split<<<dim3(LMCH/128, 16, 1), 256, 0, stream>>>(hhi, hlo,
        whi, wlo, 0,
        out + (size_t)ch * LMCH, nullptr, nullptr,
        nullptr, nullptr, nullptr, nullptr, 0,
        nullptr, nullptr, nullptr, NT, LMCH, HH, NV, 0);
  }
  bal_kernel<<<1, 64, 0, stream>>>(cnt, out + (size_t)NT * NV);
}